// Round 1
// baseline (1229.736 us; speedup 1.0000x reference)
//
#include <hip/hip_runtime.h>

#define FEAT 128

// ---------------------------------------------------------------------------
// Scatter-add: one wave per edge. Lane l handles features [2l, 2l+1].
// agg[dst] += h[src], fire-and-forget HW fp32 atomics (unsafeAtomicAdd).
// ---------------------------------------------------------------------------
__global__ __launch_bounds__(256) void scatter_add(const float* __restrict__ h,
                                                   const int* __restrict__ sidx,
                                                   const int* __restrict__ didx,
                                                   float* __restrict__ agg, int E) {
    const int e = blockIdx.x * 4 + (threadIdx.x >> 6);
    if (e >= E) return;
    const int lane = threadIdx.x & 63;
    const int s = sidx[e];
    const int d = didx[e];
    const float2 v = *(const float2*)&h[(long)s * FEAT + lane * 2];
    float* p = &agg[(long)d * FEAT + lane * 2];
    unsafeAtomicAdd(p, v.x);
    unsafeAtomicAdd(p + 1, v.y);
}

// ---------------------------------------------------------------------------
// GEMM: out[64 rows x 128 cols per block] = A @ W (+bias, optional ReLU).
// K staged in chunks of 32: W-chunk [32][128] + A-chunk transposed [32][64+pad]
// in LDS (~25 KB). Thread (tx=t&31, ty=t>>5) computes rows ty*8..ty*8+7,
// cols tx*4..tx*4+3 -> acc[8][4]. Inner loop: 3x ds_read_b128 + 32 FMA.
// ---------------------------------------------------------------------------
template <bool RELU>
__global__ __launch_bounds__(256) void gemm_128(const float* __restrict__ A,
                                                const float* __restrict__ W,
                                                const float* __restrict__ bias,
                                                float* __restrict__ out,
                                                int nrows) {
    __shared__ float wl[32][128];   // [kk][col]
    __shared__ float xl[32][68];    // [kk][row], rows padded 64->68 (16B-aligned stride)

    const int t = threadIdx.x;
    const int tx = t & 31;
    const int ty = t >> 5;              // 0..7
    const int base = blockIdx.x * 64;

    float acc[8][4];
#pragma unroll
    for (int i = 0; i < 8; i++)
#pragma unroll
        for (int j = 0; j < 4; j++) acc[i][j] = 0.f;

    for (int k0 = 0; k0 < FEAT; k0 += 32) {
        __syncthreads();
        // Stage W chunk: 32x128 floats, fully coalesced float4, linear LDS write.
#pragma unroll
        for (int it = 0; it < 4; it++) {
            const int idx = it * 1024 + t * 4;
            const int kk = idx >> 7;
            const int c = idx & 127;
            const float4 wv = *(const float4*)&W[(long)(k0 + kk) * FEAT + c];
            *(float4*)&wl[kk][c] = wv;
        }
        // Stage A chunk transposed: thread covers (row = t>>3 + 32*pass, kk = (t&7)*4).
#pragma unroll
        for (int pass = 0; pass < 2; pass++) {
            const int row = (t >> 3) + pass * 32;
            const int kk = (t & 7) * 4;
            const int g = base + row;
            float4 v = make_float4(0.f, 0.f, 0.f, 0.f);
            if (g < nrows) v = *(const float4*)&A[(long)g * FEAT + k0 + kk];
            xl[kk + 0][row] = v.x;
            xl[kk + 1][row] = v.y;
            xl[kk + 2][row] = v.z;
            xl[kk + 3][row] = v.w;
        }
        __syncthreads();
#pragma unroll
        for (int kk = 0; kk < 32; kk++) {
            const float4 wv = *(const float4*)&wl[kk][tx * 4];
            const float4 x0 = *(const float4*)&xl[kk][ty * 8];
            const float4 x1 = *(const float4*)&xl[kk][ty * 8 + 4];
            const float xs[8] = {x0.x, x0.y, x0.z, x0.w, x1.x, x1.y, x1.z, x1.w};
#pragma unroll
            for (int i = 0; i < 8; i++) {
                acc[i][0] = fmaf(xs[i], wv.x, acc[i][0]);
                acc[i][1] = fmaf(xs[i], wv.y, acc[i][1]);
                acc[i][2] = fmaf(xs[i], wv.z, acc[i][2]);
                acc[i][3] = fmaf(xs[i], wv.w, acc[i][3]);
            }
        }
    }

    const float4 bv = *(const float4*)&bias[tx * 4];
#pragma unroll
    for (int i = 0; i < 8; i++) {
        const int g = base + ty * 8 + i;
        if (g < nrows) {
            float4 o;
            o.x = acc[i][0] + bv.x;
            o.y = acc[i][1] + bv.y;
            o.z = acc[i][2] + bv.z;
            o.w = acc[i][3] + bv.w;
            if (RELU) {
                o.x = fmaxf(o.x, 0.f);
                o.y = fmaxf(o.y, 0.f);
                o.z = fmaxf(o.z, 0.f);
                o.w = fmaxf(o.w, 0.f);
            }
            *(float4*)&out[(long)g * FEAT + tx * 4] = o;
        }
    }
}

// ---------------------------------------------------------------------------
// GCN layer order exploited: segment_sum((hW)[src]) == (segment_sum h[src]) @ W.
// Aggregate first, then GEMM with fused bias (+ReLU for layer 1).
//   buf0 = scatter(x);  buf1 = relu(buf0@W1 + b1);
//   buf0 = scatter(buf1); out = buf0@W2 + b2.
// ---------------------------------------------------------------------------
extern "C" void kernel_launch(void* const* d_in, const int* in_sizes, int n_in,
                              void* d_out, int out_size, void* d_ws, size_t ws_size,
                              hipStream_t stream) {
    const float* x  = (const float*)d_in[0];
    const int*   ei = (const int*)d_in[1];
    const float* W1 = (const float*)d_in[2];
    const float* b1 = (const float*)d_in[3];
    const float* W2 = (const float*)d_in[4];
    const float* b2 = (const float*)d_in[5];
    float* out = (float*)d_out;

    const int N = in_sizes[0] / FEAT;
    const int E = in_sizes[1] / 2;
    const int* src = ei;
    const int* dst = ei + E;

    float* buf0 = (float*)d_ws;                    // N*FEAT aggregation buffer
    float* buf1 = buf0 + (size_t)N * FEAT;         // N*FEAT hidden layer
    const size_t bytes = (size_t)N * FEAT * sizeof(float);

    const int scatter_blocks = (E + 3) / 4;
    const int gemm_blocks = (N + 63) / 64;

    // Layer 1
    hipMemsetAsync(buf0, 0, bytes, stream);
    scatter_add<<<scatter_blocks, 256, 0, stream>>>(x, src, dst, buf0, E);
    gemm_128<true><<<gemm_blocks, 256, 0, stream>>>(buf0, W1, b1, buf1, N);

    // Layer 2
    hipMemsetAsync(buf0, 0, bytes, stream);
    scatter_add<<<scatter_blocks, 256, 0, stream>>>(buf1, src, dst, buf0, E);
    gemm_128<false><<<gemm_blocks, 256, 0, stream>>>(buf0, W2, b2, out, N);
}

// Round 2
// 377.198 us; speedup vs baseline: 3.2602x; 3.2602x over previous
//
#include <hip/hip_runtime.h>

#define FEAT 128

// ===========================================================================
// CSR build (counting sort on dst), once per call, reused by both layers.
// ===========================================================================

__global__ __launch_bounds__(256) void hist_kernel(const int* __restrict__ dst,
                                                   int* __restrict__ counts, int E) {
    const int e = blockIdx.x * 256 + threadIdx.x;
    if (e < E) atomicAdd(&counts[dst[e]], 1);
}

// Exclusive scan, level 1: 256 threads x 4 elems = 1024-chunk per block.
__global__ __launch_bounds__(256) void scan_chunk(const int* __restrict__ counts,
                                                  int* __restrict__ offsets,
                                                  int* __restrict__ blocksums, int N) {
    const int t = threadIdx.x;
    const int base = blockIdx.x * 1024 + t * 4;
    int c0 = (base + 0 < N) ? counts[base + 0] : 0;
    int c1 = (base + 1 < N) ? counts[base + 1] : 0;
    int c2 = (base + 2 < N) ? counts[base + 2] : 0;
    int c3 = (base + 3 < N) ? counts[base + 3] : 0;
    const int sum = c0 + c1 + c2 + c3;

    const int lane = t & 63, wv = t >> 6;
    int v = sum;
#pragma unroll
    for (int off = 1; off < 64; off <<= 1) {
        int n = __shfl_up(v, off);
        if (lane >= off) v += n;
    }
    __shared__ int ws[4];
    if (lane == 63) ws[wv] = v;
    __syncthreads();
    int wp = 0;
    for (int w = 0; w < wv; w++) wp += ws[w];
    int excl = wp + v - sum;  // exclusive prefix for this thread's 4 elems

    if (base + 0 < N) offsets[base + 0] = excl;
    if (base + 1 < N) offsets[base + 1] = excl + c0;
    if (base + 2 < N) offsets[base + 2] = excl + c0 + c1;
    if (base + 3 < N) offsets[base + 3] = excl + c0 + c1 + c2;
    if (t == 255) blocksums[blockIdx.x] = wp + v;  // chunk total
}

// Level 2: single block scans the per-chunk sums in place (exclusive).
__global__ __launch_bounds__(256) void scan_blocksums(int* __restrict__ bs, int nb) {
    const int t = threadIdx.x;
    int orig = (t < nb) ? bs[t] : 0;
    int v = orig;
    const int lane = t & 63, wv = t >> 6;
#pragma unroll
    for (int off = 1; off < 64; off <<= 1) {
        int n = __shfl_up(v, off);
        if (lane >= off) v += n;
    }
    __shared__ int ws[4];
    if (lane == 63) ws[wv] = v;
    __syncthreads();
    int wp = 0;
    for (int w = 0; w < wv; w++) wp += ws[w];
    if (t < nb) bs[t] = wp + v - orig;
}

// Level 3: add chunk base, duplicate into cursor, cap with offsets[N]=E.
__global__ __launch_bounds__(256) void add_base(int* __restrict__ offsets,
                                                int* __restrict__ cursor,
                                                const int* __restrict__ blocksums,
                                                int N, int E) {
    const int i = blockIdx.x * 256 + threadIdx.x;
    if (i < N) {
        const int off = offsets[i] + blocksums[i >> 10];
        offsets[i] = off;
        cursor[i] = off;
    }
    if (i == 0) offsets[N] = E;
}

__global__ __launch_bounds__(256) void permute_kernel(const int* __restrict__ src,
                                                      const int* __restrict__ dst,
                                                      int* __restrict__ cursor,
                                                      int* __restrict__ sorted_src, int E) {
    const int e = blockIdx.x * 256 + threadIdx.x;
    if (e < E) {
        const int pos = atomicAdd(&cursor[dst[e]], 1);
        sorted_src[pos] = src[e];
    }
}

// ===========================================================================
// Gather-reduce: one wave per node; lane l owns features [2l, 2l+1].
// agg[i] = sum_{e in [offs[i],offs[i+1])} h[sorted_src[e]]. No atomics,
// each output row written exactly once.
// ===========================================================================
__global__ __launch_bounds__(256) void gather_reduce(const float* __restrict__ h,
                                                     const int* __restrict__ offsets,
                                                     const int* __restrict__ sorted_src,
                                                     float* __restrict__ agg, int N) {
    const int i = blockIdx.x * 4 + (threadIdx.x >> 6);
    if (i >= N) return;
    const int lane = threadIdx.x & 63;
    const int start = offsets[i];
    const int end = offsets[i + 1];

    float2 acc = make_float2(0.f, 0.f);
    for (int eb = start; eb < end; eb += 64) {
        const int e = eb + lane;
        const int my_s = (e < end) ? sorted_src[e] : 0;
        const int cnt = min(64, end - eb);
        for (int j = 0; j < cnt; j++) {
            const int s = __shfl(my_s, j);
            const float2 v = *(const float2*)&h[(long)s * FEAT + lane * 2];
            acc.x += v.x;
            acc.y += v.y;
        }
    }
    *(float2*)&agg[(long)i * FEAT + lane * 2] = acc;
}

// ===========================================================================
// GEMM: out[64 rows x 128 cols per block] = A @ W (+bias, optional ReLU).
// ===========================================================================
template <bool RELU>
__global__ __launch_bounds__(256) void gemm_128(const float* __restrict__ A,
                                                const float* __restrict__ W,
                                                const float* __restrict__ bias,
                                                float* __restrict__ out,
                                                int nrows) {
    __shared__ float wl[32][128];
    __shared__ float xl[32][68];

    const int t = threadIdx.x;
    const int tx = t & 31;
    const int ty = t >> 5;
    const int base = blockIdx.x * 64;

    float acc[8][4];
#pragma unroll
    for (int i = 0; i < 8; i++)
#pragma unroll
        for (int j = 0; j < 4; j++) acc[i][j] = 0.f;

    for (int k0 = 0; k0 < FEAT; k0 += 32) {
        __syncthreads();
#pragma unroll
        for (int it = 0; it < 4; it++) {
            const int idx = it * 1024 + t * 4;
            const int kk = idx >> 7;
            const int c = idx & 127;
            *(float4*)&wl[kk][c] = *(const float4*)&W[(long)(k0 + kk) * FEAT + c];
        }
#pragma unroll
        for (int pass = 0; pass < 2; pass++) {
            const int row = (t >> 3) + pass * 32;
            const int kk = (t & 7) * 4;
            const int g = base + row;
            float4 v = make_float4(0.f, 0.f, 0.f, 0.f);
            if (g < nrows) v = *(const float4*)&A[(long)g * FEAT + k0 + kk];
            xl[kk + 0][row] = v.x;
            xl[kk + 1][row] = v.y;
            xl[kk + 2][row] = v.z;
            xl[kk + 3][row] = v.w;
        }
        __syncthreads();
#pragma unroll
        for (int kk = 0; kk < 32; kk++) {
            const float4 wv = *(const float4*)&wl[kk][tx * 4];
            const float4 x0 = *(const float4*)&xl[kk][ty * 8];
            const float4 x1 = *(const float4*)&xl[kk][ty * 8 + 4];
            const float xs[8] = {x0.x, x0.y, x0.z, x0.w, x1.x, x1.y, x1.z, x1.w};
#pragma unroll
            for (int i = 0; i < 8; i++) {
                acc[i][0] = fmaf(xs[i], wv.x, acc[i][0]);
                acc[i][1] = fmaf(xs[i], wv.y, acc[i][1]);
                acc[i][2] = fmaf(xs[i], wv.z, acc[i][2]);
                acc[i][3] = fmaf(xs[i], wv.w, acc[i][3]);
            }
        }
    }

    const float4 bv = *(const float4*)&bias[tx * 4];
#pragma unroll
    for (int i = 0; i < 8; i++) {
        const int g = base + ty * 8 + i;
        if (g < nrows) {
            float4 o;
            o.x = acc[i][0] + bv.x;
            o.y = acc[i][1] + bv.y;
            o.z = acc[i][2] + bv.z;
            o.w = acc[i][3] + bv.w;
            if (RELU) {
                o.x = fmaxf(o.x, 0.f);
                o.y = fmaxf(o.y, 0.f);
                o.z = fmaxf(o.z, 0.f);
                o.w = fmaxf(o.w, 0.f);
            }
            *(float4*)&out[(long)g * FEAT + tx * 4] = o;
        }
    }
}

// ===========================================================================
// Pipeline:  CSR(dst) built once; per layer: gather-reduce then GEMM+bias.
// Linearity: segment_sum((hW)[src]) == (segment_sum h[src]) @ W.
// CSR scratch lives in d_out (dead until final GEMM overwrites it).
// ===========================================================================
extern "C" void kernel_launch(void* const* d_in, const int* in_sizes, int n_in,
                              void* d_out, int out_size, void* d_ws, size_t ws_size,
                              hipStream_t stream) {
    const float* x  = (const float*)d_in[0];
    const int*   ei = (const int*)d_in[1];
    const float* W1 = (const float*)d_in[2];
    const float* b1 = (const float*)d_in[3];
    const float* W2 = (const float*)d_in[4];
    const float* b2 = (const float*)d_in[5];
    float* out = (float*)d_out;

    const int N = in_sizes[0] / FEAT;
    const int E = in_sizes[1] / 2;
    const int* src = ei;
    const int* dst = ei + E;

    // Workspace: two N x FEAT fp32 buffers (proven to fit from round 1).
    float* buf0 = (float*)d_ws;
    float* buf1 = buf0 + (size_t)N * FEAT;

    // CSR scratch inside d_out (3.7 MB << 51.2 MB), overwritten by final GEMM.
    int* scratch   = (int*)d_out;
    int* counts    = scratch;                 // [N]
    int* offsets   = counts + N;              // [N+1]
    int* cursor    = offsets + N + 1;         // [N]
    int* blocksums = cursor + N;              // [<=128]
    int* sorted_src = blocksums + 128;        // [E]

    const int NB = (N + 1023) / 1024;         // scan chunks (98)
    const int eb = (E + 255) / 256;
    const int nb = (N + 255) / 256;

    // ---- Build CSR ----
    hipMemsetAsync(counts, 0, (size_t)N * sizeof(int), stream);
    hist_kernel<<<eb, 256, 0, stream>>>(dst, counts, E);
    scan_chunk<<<NB, 256, 0, stream>>>(counts, offsets, blocksums, N);
    scan_blocksums<<<1, 256, 0, stream>>>(blocksums, NB);
    add_base<<<nb, 256, 0, stream>>>(offsets, cursor, blocksums, N, E);
    permute_kernel<<<eb, 256, 0, stream>>>(src, dst, cursor, sorted_src, E);

    const int gather_blocks = (N + 3) / 4;
    const int gemm_blocks = (N + 63) / 64;

    // ---- Layer 1 ----
    gather_reduce<<<gather_blocks, 256, 0, stream>>>(x, offsets, sorted_src, buf0, N);
    gemm_128<true><<<gemm_blocks, 256, 0, stream>>>(buf0, W1, b1, buf1, N);

    // ---- Layer 2 ----
    gather_reduce<<<gather_blocks, 256, 0, stream>>>(buf1, offsets, sorted_src, buf0, N);
    gemm_128<false><<<gemm_blocks, 256, 0, stream>>>(buf0, W2, b2, out, N);
}

// Round 3
// 321.987 us; speedup vs baseline: 3.8192x; 1.1715x over previous
//
#include <hip/hip_runtime.h>

#define FEAT 128

typedef __attribute__((ext_vector_type(8))) short short8;
typedef __attribute__((ext_vector_type(4))) float floatx4;

// bf16 helpers (manual, RNE) — avoids header type friction, finite data only.
__device__ __forceinline__ unsigned short f2bf(float f) {
    unsigned int u = __float_as_uint(f);
    u += 0x7fffu + ((u >> 16) & 1u);
    return (unsigned short)(u >> 16);
}
__device__ __forceinline__ float bf_lo(unsigned int u) { return __uint_as_float(u << 16); }
__device__ __forceinline__ float bf_hi(unsigned int u) { return __uint_as_float(u & 0xffff0000u); }

// ===========================================================================
// CSR build (counting sort on dst), once per call, reused by both layers.
// ===========================================================================
__global__ __launch_bounds__(256) void hist_kernel(const int* __restrict__ dst,
                                                   int* __restrict__ counts, int E) {
    const int e = blockIdx.x * 256 + threadIdx.x;
    if (e < E) atomicAdd(&counts[dst[e]], 1);
}

__global__ __launch_bounds__(256) void scan_chunk(const int* __restrict__ counts,
                                                  int* __restrict__ offsets,
                                                  int* __restrict__ blocksums, int N) {
    const int t = threadIdx.x;
    const int base = blockIdx.x * 1024 + t * 4;
    int c0 = (base + 0 < N) ? counts[base + 0] : 0;
    int c1 = (base + 1 < N) ? counts[base + 1] : 0;
    int c2 = (base + 2 < N) ? counts[base + 2] : 0;
    int c3 = (base + 3 < N) ? counts[base + 3] : 0;
    const int sum = c0 + c1 + c2 + c3;

    const int lane = t & 63, wv = t >> 6;
    int v = sum;
#pragma unroll
    for (int off = 1; off < 64; off <<= 1) {
        int n = __shfl_up(v, off);
        if (lane >= off) v += n;
    }
    __shared__ int ws[4];
    if (lane == 63) ws[wv] = v;
    __syncthreads();
    int wp = 0;
    for (int w = 0; w < wv; w++) wp += ws[w];
    int excl = wp + v - sum;

    if (base + 0 < N) offsets[base + 0] = excl;
    if (base + 1 < N) offsets[base + 1] = excl + c0;
    if (base + 2 < N) offsets[base + 2] = excl + c0 + c1;
    if (base + 3 < N) offsets[base + 3] = excl + c0 + c1 + c2;
    if (t == 255) blocksums[blockIdx.x] = wp + v;
}

__global__ __launch_bounds__(256) void scan_blocksums(int* __restrict__ bs, int nb) {
    const int t = threadIdx.x;
    int orig = (t < nb) ? bs[t] : 0;
    int v = orig;
    const int lane = t & 63, wv = t >> 6;
#pragma unroll
    for (int off = 1; off < 64; off <<= 1) {
        int n = __shfl_up(v, off);
        if (lane >= off) v += n;
    }
    __shared__ int ws[4];
    if (lane == 63) ws[wv] = v;
    __syncthreads();
    int wp = 0;
    for (int w = 0; w < wv; w++) wp += ws[w];
    if (t < nb) bs[t] = wp + v - orig;
}

__global__ __launch_bounds__(256) void add_base(int* __restrict__ offsets,
                                                int* __restrict__ cursor,
                                                const int* __restrict__ blocksums,
                                                int N, int E) {
    const int i = blockIdx.x * 256 + threadIdx.x;
    if (i < N) {
        const int off = offsets[i] + blocksums[i >> 10];
        offsets[i] = off;
        cursor[i] = off;
    }
    if (i == 0) offsets[N] = E;
}

__global__ __launch_bounds__(256) void permute_kernel(const int* __restrict__ src,
                                                      const int* __restrict__ dst,
                                                      int* __restrict__ cursor,
                                                      int* __restrict__ sorted_src, int E) {
    const int e = blockIdx.x * 256 + threadIdx.x;
    if (e < E) {
        const int pos = atomicAdd(&cursor[dst[e]], 1);
        sorted_src[pos] = src[e];
    }
}

// ===========================================================================
// fp32 [N,128] -> bf16 [N,128] (RNE). 4 elems/thread.
// ===========================================================================
__global__ __launch_bounds__(256) void convert_bf16(const float* __restrict__ in,
                                                    unsigned short* __restrict__ out,
                                                    long n4) {
    const long i = (long)blockIdx.x * 256 + threadIdx.x;
    if (i >= n4) return;
    const float4 v = *(const float4*)&in[i * 4];
    uint2 p;
    p.x = (unsigned int)f2bf(v.x) | ((unsigned int)f2bf(v.y) << 16);
    p.y = (unsigned int)f2bf(v.z) | ((unsigned int)f2bf(v.w) << 16);
    *(uint2*)&out[i * 4] = p;
}

// ===========================================================================
// W [128,128] fp32 -> fragment-ordered bf16 for mfma_f32_16x16x32_bf16.
// bfW[((kc*8+ct)*64+lane)*8 + j] = bf16(W[kc*32 + (lane>>4)*8 + j][ct*16 + (lane&15)])
// One block, 256 threads x 8 iters covers 2048 (kc,ct,lane) tuples.
// ===========================================================================
__global__ __launch_bounds__(256) void prep_w(const float* __restrict__ W,
                                              unsigned short* __restrict__ bfW) {
    const int t = threadIdx.x;
#pragma unroll
    for (int it = 0; it < 8; it++) {
        const int idx = it * 256 + t;          // 0..2047
        const int kc = idx >> 9;               // 0..3
        const int ct = (idx >> 6) & 7;         // 0..7
        const int lane = idx & 63;
        const int quad = lane >> 4;
        const int n = ct * 16 + (lane & 15);
        unsigned short frag[8];
#pragma unroll
        for (int j = 0; j < 8; j++) {
            const int k = kc * 32 + quad * 8 + j;
            frag[j] = f2bf(W[k * FEAT + n]);
        }
        // 16B store
        *(uint4*)&bfW[(long)idx * 8] = *(uint4*)frag;
    }
}

// ===========================================================================
// Gather-reduce (bf16 payload): one wave per node; lane l owns features
// [2l, 2l+1] (one packed uint). Accumulate fp32, write packed bf16.
// ===========================================================================
__global__ __launch_bounds__(256) void gather_reduce_bf(const unsigned short* __restrict__ h,
                                                        const int* __restrict__ offsets,
                                                        const int* __restrict__ sorted_src,
                                                        unsigned short* __restrict__ agg, int N) {
    const int i = blockIdx.x * 4 + (threadIdx.x >> 6);
    if (i >= N) return;
    const int lane = threadIdx.x & 63;
    const int start = offsets[i];
    const int end = offsets[i + 1];
    const unsigned int* hb = (const unsigned int*)h;  // 64 uints per row

    float2 acc = make_float2(0.f, 0.f);
    for (int eb = start; eb < end; eb += 64) {
        const int e = eb + lane;
        const int my_s = (e < end) ? sorted_src[e] : 0;
        const int cnt = min(64, end - eb);
        for (int j = 0; j < cnt; j++) {
            const int s = __shfl(my_s, j);
            const unsigned int u = hb[(long)s * 64 + lane];
            acc.x += bf_lo(u);
            acc.y += bf_hi(u);
        }
    }
    unsigned int p = (unsigned int)f2bf(acc.x) | ((unsigned int)f2bf(acc.y) << 16);
    ((unsigned int*)agg)[(long)i * 64 + lane] = p;
}

// ===========================================================================
// MFMA GEMM: [nrows,128] bf16 @ [128,128] (frag-ordered bf16 W in LDS)
// Block = 4 waves x 16 rows = 64 rows. Wave computes 16x128 via 32 MFMAs.
// Epilogue: +bias, optional ReLU; OUT_BF16 -> bf16 (for next gather) else fp32.
// ===========================================================================
template <bool RELU, bool OUT_BF16>
__global__ __launch_bounds__(256) void gemm_mfma(const unsigned short* __restrict__ A,
                                                 const unsigned short* __restrict__ bfW,
                                                 const float* __restrict__ bias,
                                                 void* __restrict__ out, int nrows) {
    __shared__ unsigned short sB[16384];  // 32 KB frag-ordered W

    const int t = threadIdx.x;
    // Stage frag-ordered W linearly: 32768 B / (256*16 B) = 8 iters.
#pragma unroll
    for (int it = 0; it < 8; it++) {
        const int o = (it * 256 + t) * 8;  // ushort index, 16B chunks
        *(uint4*)&sB[o] = *(const uint4*)&bfW[o];
    }
    __syncthreads();

    const int wave = t >> 6;
    const int lane = t & 63;
    const int quad = lane >> 4;
    const int l15 = lane & 15;
    const int row0 = blockIdx.x * 64 + wave * 16;   // wave's 16-row slab
    const int arow = min(row0 + l15, nrows - 1);    // clamped A row (guard stores later)

    // Load all 4 A k-chunk fragments: 16B each, 64B/row segments, coalesced.
    short8 afrag[4];
#pragma unroll
    for (int kc = 0; kc < 4; kc++)
        afrag[kc] = *(const short8*)&A[(long)arow * FEAT + kc * 32 + quad * 8];

    floatx4 acc[8];
#pragma unroll
    for (int ct = 0; ct < 8; ct++) acc[ct] = (floatx4){0.f, 0.f, 0.f, 0.f};

#pragma unroll
    for (int kc = 0; kc < 4; kc++) {
#pragma unroll
        for (int ct = 0; ct < 8; ct++) {
            const short8 b = *(const short8*)&sB[((kc * 8 + ct) * 64 + lane) * 8];
            acc[ct] = __builtin_amdgcn_mfma_f32_16x16x32_bf16(afrag[kc], b, acc[ct], 0, 0, 0);
        }
    }

    // Epilogue: C/D layout col = lane&15, row = quad*4 + r.
#pragma unroll
    for (int ct = 0; ct < 8; ct++) {
        const int col = ct * 16 + l15;
        const float bv = bias[col];
#pragma unroll
        for (int r = 0; r < 4; r++) {
            const int row = row0 + quad * 4 + r;
            if (row < nrows) {
                float v = acc[ct][r] + bv;
                if (RELU) v = fmaxf(v, 0.f);
                if (OUT_BF16)
                    ((unsigned short*)out)[(long)row * FEAT + col] = f2bf(v);
                else
                    ((float*)out)[(long)row * FEAT + col] = v;
            }
        }
    }
}

// ===========================================================================
// Pipeline (all bf16 payloads, fp32 accumulation):
//   CSR(dst) once; xb = bf16(x)
//   aggb = gather(xb);  h1b = bf16(relu(aggb@W1 + b1))   [MFMA]
//   aggb = gather(h1b); out  = aggb@W2 + b2  (fp32)      [MFMA]
// Linearity: segment_sum((hW)[src]) == (segment_sum h[src]) @ W.
// ===========================================================================
extern "C" void kernel_launch(void* const* d_in, const int* in_sizes, int n_in,
                              void* d_out, int out_size, void* d_ws, size_t ws_size,
                              hipStream_t stream) {
    const float* x  = (const float*)d_in[0];
    const int*   ei = (const int*)d_in[1];
    const float* W1 = (const float*)d_in[2];
    const float* b1 = (const float*)d_in[3];
    const float* W2 = (const float*)d_in[4];
    const float* b2 = (const float*)d_in[5];
    float* out = (float*)d_out;

    const int N = in_sizes[0] / FEAT;
    const int E = in_sizes[1] / 2;
    const int* src = ei;
    const int* dst = ei + E;

    // Workspace carve-up (~80.5 MB; round-1 proved >=102.4 MB available).
    unsigned short* xb   = (unsigned short*)d_ws;            // N*128 bf16
    unsigned short* h1b  = xb + (size_t)N * FEAT;            // N*128 bf16
    unsigned short* aggb = h1b + (size_t)N * FEAT;           // N*128 bf16
    unsigned short* bfW1 = aggb + (size_t)N * FEAT;          // 16384
    unsigned short* bfW2 = bfW1 + 16384;                     // 16384
    int* counts    = (int*)(bfW2 + 16384);                   // [N]
    int* offsets   = counts + N;                             // [N+1]
    int* cursor    = offsets + N + 1;                        // [N]
    int* blocksums = cursor + N;                             // [<=128]
    int* sorted_src = blocksums + 128;                       // [E]

    const int NB = (N + 1023) / 1024;
    const int eb = (E + 255) / 256;
    const int nb = (N + 255) / 256;

    // ---- CSR build ----
    hipMemsetAsync(counts, 0, (size_t)N * sizeof(int), stream);
    hist_kernel<<<eb, 256, 0, stream>>>(dst, counts, E);
    scan_chunk<<<NB, 256, 0, stream>>>(counts, offsets, blocksums, N);
    scan_blocksums<<<1, 256, 0, stream>>>(blocksums, NB);
    add_base<<<nb, 256, 0, stream>>>(offsets, cursor, blocksums, N, E);
    permute_kernel<<<eb, 256, 0, stream>>>(src, dst, cursor, sorted_src, E);

    // ---- bf16 prep ----
    const long n4 = (long)N * FEAT / 4;
    convert_bf16<<<(int)((n4 + 255) / 256), 256, 0, stream>>>(x, xb, n4);
    prep_w<<<1, 256, 0, stream>>>(W1, bfW1);
    prep_w<<<1, 256, 0, stream>>>(W2, bfW2);

    const int gather_blocks = (N + 3) / 4;
    const int gemm_blocks = (N + 63) / 64;

    // ---- Layer 1 ----
    gather_reduce_bf<<<gather_blocks, 256, 0, stream>>>(xb, offsets, sorted_src, aggb, N);
    gemm_mfma<true, true><<<gemm_blocks, 256, 0, stream>>>(aggb, bfW1, b1, h1b, N);

    // ---- Layer 2 ----
    gather_reduce_bf<<<gather_blocks, 256, 0, stream>>>(h1b, offsets, sorted_src, aggb, N);
    gemm_mfma<false, false><<<gemm_blocks, 256, 0, stream>>>(aggb, bfW2, b2, out, N);
}

// Round 4
// 267.375 us; speedup vs baseline: 4.5993x; 1.2043x over previous
//
#include <hip/hip_runtime.h>

#define FEAT 128

typedef __attribute__((ext_vector_type(8))) short short8;
typedef __attribute__((ext_vector_type(4))) float floatx4;

// bf16 helpers (manual, RNE) — finite data only.
__device__ __forceinline__ unsigned short f2bf(float f) {
    unsigned int u = __float_as_uint(f);
    u += 0x7fffu + ((u >> 16) & 1u);
    return (unsigned short)(u >> 16);
}
__device__ __forceinline__ float bf_lo(unsigned int u) { return __uint_as_float(u << 16); }
__device__ __forceinline__ float bf_hi(unsigned int u) { return __uint_as_float(u & 0xffff0000u); }
__device__ __forceinline__ unsigned int pack2(float a, float b) {
    return (unsigned int)f2bf(a) | ((unsigned int)f2bf(b) << 16);
}

// ===========================================================================
// CSR build (counting sort on dst), once per call, reused by both layers.
// ===========================================================================
__global__ __launch_bounds__(256) void hist_kernel(const int* __restrict__ dst,
                                                   int* __restrict__ counts, int E) {
    const int e = blockIdx.x * 256 + threadIdx.x;
    if (e < E) atomicAdd(&counts[dst[e]], 1);
}

__global__ __launch_bounds__(256) void scan_chunk(const int* __restrict__ counts,
                                                  int* __restrict__ offsets,
                                                  int* __restrict__ blocksums, int N) {
    const int t = threadIdx.x;
    const int base = blockIdx.x * 1024 + t * 4;
    int c0 = (base + 0 < N) ? counts[base + 0] : 0;
    int c1 = (base + 1 < N) ? counts[base + 1] : 0;
    int c2 = (base + 2 < N) ? counts[base + 2] : 0;
    int c3 = (base + 3 < N) ? counts[base + 3] : 0;
    const int sum = c0 + c1 + c2 + c3;

    const int lane = t & 63, wv = t >> 6;
    int v = sum;
#pragma unroll
    for (int off = 1; off < 64; off <<= 1) {
        int n = __shfl_up(v, off);
        if (lane >= off) v += n;
    }
    __shared__ int ws[4];
    if (lane == 63) ws[wv] = v;
    __syncthreads();
    int wp = 0;
    for (int w = 0; w < wv; w++) wp += ws[w];
    int excl = wp + v - sum;

    if (base + 0 < N) offsets[base + 0] = excl;
    if (base + 1 < N) offsets[base + 1] = excl + c0;
    if (base + 2 < N) offsets[base + 2] = excl + c0 + c1;
    if (base + 3 < N) offsets[base + 3] = excl + c0 + c1 + c2;
    if (t == 255) blocksums[blockIdx.x] = wp + v;
}

__global__ __launch_bounds__(256) void scan_blocksums(int* __restrict__ bs, int nb) {
    const int t = threadIdx.x;
    int orig = (t < nb) ? bs[t] : 0;
    int v = orig;
    const int lane = t & 63, wv = t >> 6;
#pragma unroll
    for (int off = 1; off < 64; off <<= 1) {
        int n = __shfl_up(v, off);
        if (lane >= off) v += n;
    }
    __shared__ int ws[4];
    if (lane == 63) ws[wv] = v;
    __syncthreads();
    int wp = 0;
    for (int w = 0; w < wv; w++) wp += ws[w];
    if (t < nb) bs[t] = wp + v - orig;
}

__global__ __launch_bounds__(256) void add_base(int* __restrict__ offsets,
                                                int* __restrict__ cursor,
                                                const int* __restrict__ blocksums,
                                                int N, int E) {
    const int i = blockIdx.x * 256 + threadIdx.x;
    if (i < N) {
        const int off = offsets[i] + blocksums[i >> 10];
        offsets[i] = off;
        cursor[i] = off;
    }
    if (i == 0) offsets[N] = E;
}

__global__ __launch_bounds__(256) void permute_kernel(const int* __restrict__ src,
                                                      const int* __restrict__ dst,
                                                      int* __restrict__ cursor,
                                                      int* __restrict__ sorted_src, int E) {
    const int e = blockIdx.x * 256 + threadIdx.x;
    if (e < E) {
        const int pos = atomicAdd(&cursor[dst[e]], 1);
        sorted_src[pos] = src[e];
    }
}

// ===========================================================================
// fp32 [N,128] -> bf16 (RNE), 4 elems/thread.
// ===========================================================================
__global__ __launch_bounds__(256) void convert_bf16(const float* __restrict__ in,
                                                    unsigned short* __restrict__ out,
                                                    long n4) {
    const long i = (long)blockIdx.x * 256 + threadIdx.x;
    if (i >= n4) return;
    const float4 v = *(const float4*)&in[i * 4];
    uint2 p;
    p.x = pack2(v.x, v.y);
    p.y = pack2(v.z, v.w);
    *(uint2*)&out[i * 4] = p;
}

// ===========================================================================
// Both W matrices -> fragment-ordered bf16 for mfma_f32_16x16x32_bf16.
// bfW[((kc*8+ct)*64+lane)*8 + j] = bf16(W[kc*32 + (lane>>4)*8 + j][ct*16 + (lane&15)])
// blockIdx 0 -> W1, 1 -> W2.
// ===========================================================================
__global__ __launch_bounds__(256) void prep_w2(const float* __restrict__ W1,
                                               const float* __restrict__ W2,
                                               unsigned short* __restrict__ bfW1,
                                               unsigned short* __restrict__ bfW2) {
    const float* W = blockIdx.x ? W2 : W1;
    unsigned short* bfW = blockIdx.x ? bfW2 : bfW1;
    const int t = threadIdx.x;
#pragma unroll
    for (int it = 0; it < 8; it++) {
        const int idx = it * 256 + t;
        const int kc = idx >> 9;
        const int ct = (idx >> 6) & 7;
        const int lane = idx & 63;
        const int quad = lane >> 4;
        const int n = ct * 16 + (lane & 15);
        unsigned short frag[8];
#pragma unroll
        for (int j = 0; j < 8; j++) {
            const int k = kc * 32 + quad * 8 + j;
            frag[j] = f2bf(W[k * FEAT + n]);
        }
        *(uint4*)&bfW[(long)idx * 8] = *(uint4*)frag;
    }
}

// ===========================================================================
// Gather-reduce (bf16): 16 lanes per node (4 nodes/wave, 16 nodes/block).
// Lane g=t&15 owns feats [8g,8g+8) = one dwordx4 of the 256 B row.
// 4 independent load streams/wave + 2-way unroll for MLP. fp32 accum.
// ===========================================================================
__global__ __launch_bounds__(256) void gather_reduce_bf(const unsigned short* __restrict__ h,
                                                        const int* __restrict__ offsets,
                                                        const int* __restrict__ sorted_src,
                                                        unsigned short* __restrict__ agg, int N) {
    const int t = threadIdx.x;
    const int g16 = t & 15;
    const int grpbase = t & 48;          // == (lane & 48): group's base lane in wave
    const int i = blockIdx.x * 16 + (t >> 4);

    int start = 0, end = 0;
    if (i < N) { start = offsets[i]; end = offsets[i + 1]; }

    const uint4* hb = (const uint4*)h;   // 16 uint4 per 128-feat row
    float acc[8] = {0.f, 0.f, 0.f, 0.f, 0.f, 0.f, 0.f, 0.f};

    for (int eb = start; eb < end; eb += 16) {
        const int e = eb + g16;
        const int my_s = (e < end) ? sorted_src[e] : 0;
        const int cnt = min(16, end - eb);
        int j = 0;
        for (; j + 1 < cnt; j += 2) {
            const int s0 = __shfl(my_s, grpbase + j);
            const int s1 = __shfl(my_s, grpbase + j + 1);
            const uint4 u0 = hb[(long)s0 * 16 + g16];
            const uint4 u1 = hb[(long)s1 * 16 + g16];
            acc[0] += bf_lo(u0.x); acc[1] += bf_hi(u0.x);
            acc[2] += bf_lo(u0.y); acc[3] += bf_hi(u0.y);
            acc[4] += bf_lo(u0.z); acc[5] += bf_hi(u0.z);
            acc[6] += bf_lo(u0.w); acc[7] += bf_hi(u0.w);
            acc[0] += bf_lo(u1.x); acc[1] += bf_hi(u1.x);
            acc[2] += bf_lo(u1.y); acc[3] += bf_hi(u1.y);
            acc[4] += bf_lo(u1.z); acc[5] += bf_hi(u1.z);
            acc[6] += bf_lo(u1.w); acc[7] += bf_hi(u1.w);
        }
        if (j < cnt) {
            const int s0 = __shfl(my_s, grpbase + j);
            const uint4 u0 = hb[(long)s0 * 16 + g16];
            acc[0] += bf_lo(u0.x); acc[1] += bf_hi(u0.x);
            acc[2] += bf_lo(u0.y); acc[3] += bf_hi(u0.y);
            acc[4] += bf_lo(u0.z); acc[5] += bf_hi(u0.z);
            acc[6] += bf_lo(u0.w); acc[7] += bf_hi(u0.w);
        }
    }

    if (i < N) {
        uint4 p;
        p.x = pack2(acc[0], acc[1]);
        p.y = pack2(acc[2], acc[3]);
        p.z = pack2(acc[4], acc[5]);
        p.w = pack2(acc[6], acc[7]);
        ((uint4*)agg)[(long)i * 16 + g16] = p;
    }
}

// ===========================================================================
// MFMA GEMM: [nrows,128] bf16 @ [128,128] (frag-ordered W in LDS).
// Block = 4 waves x 16 rows. Epilogue transposes through LDS (stride 132:
// only 2-way bank aliasing, free) then stores coalesced uint4/float4 rows.
// ===========================================================================
template <bool RELU, bool OUT_BF16>
__global__ __launch_bounds__(256) void gemm_mfma(const unsigned short* __restrict__ A,
                                                 const unsigned short* __restrict__ bfW,
                                                 const float* __restrict__ bias,
                                                 void* __restrict__ out, int nrows) {
    __shared__ __align__(16) union {
        unsigned short b[16384];   // 32 KB frag-ordered W
        float o[64 * 132];         // 33.8 KB epilogue transpose
    } sm;

    const int t = threadIdx.x;
#pragma unroll
    for (int it = 0; it < 8; it++) {
        const int o = (it * 256 + t) * 8;
        *(uint4*)&sm.b[o] = *(const uint4*)&bfW[o];
    }
    __syncthreads();

    const int wave = t >> 6;
    const int lane = t & 63;
    const int quad = lane >> 4;
    const int l15 = lane & 15;
    const int row0 = blockIdx.x * 64 + wave * 16;
    const int arow = min(row0 + l15, nrows - 1);

    short8 afrag[4];
#pragma unroll
    for (int kc = 0; kc < 4; kc++)
        afrag[kc] = *(const short8*)&A[(long)arow * FEAT + kc * 32 + quad * 8];

    floatx4 acc[8];
#pragma unroll
    for (int ct = 0; ct < 8; ct++) acc[ct] = (floatx4){0.f, 0.f, 0.f, 0.f};

#pragma unroll
    for (int kc = 0; kc < 4; kc++) {
#pragma unroll
        for (int ct = 0; ct < 8; ct++) {
            const short8 b = *(const short8*)&sm.b[((kc * 8 + ct) * 64 + lane) * 8];
            acc[ct] = __builtin_amdgcn_mfma_f32_16x16x32_bf16(afrag[kc], b, acc[ct], 0, 0, 0);
        }
    }

    __syncthreads();  // all waves done reading sm.b
    // C/D layout: col = lane&15, row = quad*4 + r. Apply bias/ReLU, park in LDS.
#pragma unroll
    for (int ct = 0; ct < 8; ct++) {
        const int col = ct * 16 + l15;
        const float bv = bias[col];
#pragma unroll
        for (int r = 0; r < 4; r++) {
            float v = acc[ct][r] + bv;
            if (RELU) v = fmaxf(v, 0.f);
            sm.o[(wave * 16 + quad * 4 + r) * 132 + col] = v;
        }
    }
    __syncthreads();

    // Coalesced store: thread covers row rb = t>>2, cols [(t&3)*32, +32).
    const int rb = t >> 2;
    const int c0 = (t & 3) * 32;
    const int grow = blockIdx.x * 64 + rb;
    if (grow < nrows) {
        const float* lr = &sm.o[rb * 132 + c0];
        if (OUT_BF16) {
            unsigned short* op = (unsigned short*)out + (long)grow * FEAT + c0;
#pragma unroll
            for (int k = 0; k < 4; k++) {
                const float4 a = *(const float4*)&lr[k * 8];
                const float4 b = *(const float4*)&lr[k * 8 + 4];
                uint4 p;
                p.x = pack2(a.x, a.y);
                p.y = pack2(a.z, a.w);
                p.z = pack2(b.x, b.y);
                p.w = pack2(b.z, b.w);
                *(uint4*)&op[k * 8] = p;
            }
        } else {
            float* op = (float*)out + (long)grow * FEAT + c0;
#pragma unroll
            for (int k = 0; k < 8; k++)
                *(float4*)&op[k * 4] = *(const float4*)&lr[k * 4];
        }
    }
}

// ===========================================================================
// Pipeline (bf16 payloads, fp32 accumulation):
//   CSR(dst) once; xb = bf16(x)
//   aggb = gather(xb);  h1b = bf16(relu(aggb@W1 + b1))   [MFMA]
//   aggb = gather(h1b); out  = aggb@W2 + b2  (fp32)      [MFMA]
// Linearity: segment_sum((hW)[src]) == (segment_sum h[src]) @ W.
// ===========================================================================
extern "C" void kernel_launch(void* const* d_in, const int* in_sizes, int n_in,
                              void* d_out, int out_size, void* d_ws, size_t ws_size,
                              hipStream_t stream) {
    const float* x  = (const float*)d_in[0];
    const int*   ei = (const int*)d_in[1];
    const float* W1 = (const float*)d_in[2];
    const float* b1 = (const float*)d_in[3];
    const float* W2 = (const float*)d_in[4];
    const float* b2 = (const float*)d_in[5];
    float* out = (float*)d_out;

    const int N = in_sizes[0] / FEAT;
    const int E = in_sizes[1] / 2;
    const int* src = ei;
    const int* dst = ei + E;

    // Workspace carve-up (~80.5 MB; >=102.4 MB proven available in round 1).
    unsigned short* xb   = (unsigned short*)d_ws;            // N*128 bf16
    unsigned short* h1b  = xb + (size_t)N * FEAT;            // N*128 bf16
    unsigned short* aggb = h1b + (size_t)N * FEAT;           // N*128 bf16
    unsigned short* bfW1 = aggb + (size_t)N * FEAT;          // 16384
    unsigned short* bfW2 = bfW1 + 16384;                     // 16384
    int* counts    = (int*)(bfW2 + 16384);                   // [N]
    int* offsets   = counts + N;                             // [N+1]
    int* cursor    = offsets + N + 1;                        // [N]
    int* blocksums = cursor + N;                             // [<=128]
    int* sorted_src = blocksums + 128;                       // [E]

    const int NB = (N + 1023) / 1024;
    const int eb = (E + 255) / 256;
    const int nb = (N + 255) / 256;

    // ---- CSR build ----
    hipMemsetAsync(counts, 0, (size_t)N * sizeof(int), stream);
    hist_kernel<<<eb, 256, 0, stream>>>(dst, counts, E);
    scan_chunk<<<NB, 256, 0, stream>>>(counts, offsets, blocksums, N);
    scan_blocksums<<<1, 256, 0, stream>>>(blocksums, NB);
    add_base<<<nb, 256, 0, stream>>>(offsets, cursor, blocksums, N, E);
    permute_kernel<<<eb, 256, 0, stream>>>(src, dst, cursor, sorted_src, E);

    // ---- bf16 prep ----
    const long n4 = (long)N * FEAT / 4;
    convert_bf16<<<(int)((n4 + 255) / 256), 256, 0, stream>>>(x, xb, n4);
    prep_w2<<<2, 256, 0, stream>>>(W1, W2, bfW1, bfW2);

    const int gather_blocks = (N + 15) / 16;
    const int gemm_blocks = (N + 63) / 64;

    // ---- Layer 1 ----
    gather_reduce_bf<<<gather_blocks, 256, 0, stream>>>(xb, offsets, sorted_src, aggb, N);
    gemm_mfma<true, true><<<gemm_blocks, 256, 0, stream>>>(aggb, bfW1, b1, h1b, N);

    // ---- Layer 2 ----
    gather_reduce_bf<<<gather_blocks, 256, 0, stream>>>(h1b, offsets, sorted_src, aggb, N);
    gemm_mfma<false, false><<<gemm_blocks, 256, 0, stream>>>(aggb, bfW2, b2, out, N);
}

// Round 5
// 265.916 us; speedup vs baseline: 4.6245x; 1.0055x over previous
//
#include <hip/hip_runtime.h>

#define FEAT 128

typedef __attribute__((ext_vector_type(8))) short short8;
typedef __attribute__((ext_vector_type(4))) float floatx4;

// bf16 helpers (manual, RNE) — finite data only.
__device__ __forceinline__ unsigned short f2bf(float f) {
    unsigned int u = __float_as_uint(f);
    u += 0x7fffu + ((u >> 16) & 1u);
    return (unsigned short)(u >> 16);
}
__device__ __forceinline__ float bf_lo(unsigned int u) { return __uint_as_float(u << 16); }
__device__ __forceinline__ float bf_hi(unsigned int u) { return __uint_as_float(u & 0xffff0000u); }
__device__ __forceinline__ unsigned int pack2(float a, float b) {
    return (unsigned int)f2bf(a) | ((unsigned int)f2bf(b) << 16);
}

// ===========================================================================
// CSR build (counting sort on dst), once per call, reused by both layers.
// ===========================================================================
__global__ __launch_bounds__(256) void hist_kernel(const int* __restrict__ dst,
                                                   int* __restrict__ counts, int E) {
    const int e = blockIdx.x * 256 + threadIdx.x;
    if (e < E) atomicAdd(&counts[dst[e]], 1);
}

__global__ __launch_bounds__(256) void scan_chunk(const int* __restrict__ counts,
                                                  int* __restrict__ offsets,
                                                  int* __restrict__ blocksums, int N) {
    const int t = threadIdx.x;
    const int base = blockIdx.x * 1024 + t * 4;
    int c0 = (base + 0 < N) ? counts[base + 0] : 0;
    int c1 = (base + 1 < N) ? counts[base + 1] : 0;
    int c2 = (base + 2 < N) ? counts[base + 2] : 0;
    int c3 = (base + 3 < N) ? counts[base + 3] : 0;
    const int sum = c0 + c1 + c2 + c3;

    const int lane = t & 63, wv = t >> 6;
    int v = sum;
#pragma unroll
    for (int off = 1; off < 64; off <<= 1) {
        int n = __shfl_up(v, off);
        if (lane >= off) v += n;
    }
    __shared__ int ws[4];
    if (lane == 63) ws[wv] = v;
    __syncthreads();
    int wp = 0;
    for (int w = 0; w < wv; w++) wp += ws[w];
    int excl = wp + v - sum;

    if (base + 0 < N) offsets[base + 0] = excl;
    if (base + 1 < N) offsets[base + 1] = excl + c0;
    if (base + 2 < N) offsets[base + 2] = excl + c0 + c1;
    if (base + 3 < N) offsets[base + 3] = excl + c0 + c1 + c2;
    if (t == 255) blocksums[blockIdx.x] = wp + v;
}

__global__ __launch_bounds__(256) void scan_blocksums(int* __restrict__ bs, int nb) {
    const int t = threadIdx.x;
    int orig = (t < nb) ? bs[t] : 0;
    int v = orig;
    const int lane = t & 63, wv = t >> 6;
#pragma unroll
    for (int off = 1; off < 64; off <<= 1) {
        int n = __shfl_up(v, off);
        if (lane >= off) v += n;
    }
    __shared__ int ws[4];
    if (lane == 63) ws[wv] = v;
    __syncthreads();
    int wp = 0;
    for (int w = 0; w < wv; w++) wp += ws[w];
    if (t < nb) bs[t] = wp + v - orig;
}

__global__ __launch_bounds__(256) void add_base(int* __restrict__ offsets,
                                                int* __restrict__ cursor,
                                                const int* __restrict__ blocksums,
                                                int N, int E) {
    const int i = blockIdx.x * 256 + threadIdx.x;
    if (i < N) {
        const int off = offsets[i] + blocksums[i >> 10];
        offsets[i] = off;
        cursor[i] = off;
    }
    if (i == 0) offsets[N] = E;
}

__global__ __launch_bounds__(256) void permute_kernel(const int* __restrict__ src,
                                                      const int* __restrict__ dst,
                                                      int* __restrict__ cursor,
                                                      int* __restrict__ sorted_src, int E) {
    const int e = blockIdx.x * 256 + threadIdx.x;
    if (e < E) {
        const int pos = atomicAdd(&cursor[dst[e]], 1);
        sorted_src[pos] = src[e];
    }
}

// ===========================================================================
// fp32 [N,128] -> bf16 (RNE), 4 elems/thread.
// ===========================================================================
__global__ __launch_bounds__(256) void convert_bf16(const float* __restrict__ in,
                                                    unsigned short* __restrict__ out,
                                                    long n4) {
    const long i = (long)blockIdx.x * 256 + threadIdx.x;
    if (i >= n4) return;
    const float4 v = *(const float4*)&in[i * 4];
    uint2 p;
    p.x = pack2(v.x, v.y);
    p.y = pack2(v.z, v.w);
    *(uint2*)&out[i * 4] = p;
}

// ===========================================================================
// Both W matrices -> fragment-ordered bf16 for mfma_f32_16x16x32_bf16.
// bfW[((kc*8+ct)*64+lane)*8 + j] = bf16(W[kc*32 + (lane>>4)*8 + j][ct*16 + (lane&15)])
// blockIdx 0 -> W1, 1 -> W2.
// ===========================================================================
__global__ __launch_bounds__(256) void prep_w2(const float* __restrict__ W1,
                                               const float* __restrict__ W2,
                                               unsigned short* __restrict__ bfW1,
                                               unsigned short* __restrict__ bfW2) {
    const float* W = blockIdx.x ? W2 : W1;
    unsigned short* bfW = blockIdx.x ? bfW2 : bfW1;
    const int t = threadIdx.x;
#pragma unroll
    for (int it = 0; it < 8; it++) {
        const int idx = it * 256 + t;
        const int kc = idx >> 9;
        const int ct = (idx >> 6) & 7;
        const int lane = idx & 63;
        const int quad = lane >> 4;
        const int n = ct * 16 + (lane & 15);
        unsigned short frag[8];
#pragma unroll
        for (int j = 0; j < 8; j++) {
            const int k = kc * 32 + quad * 8 + j;
            frag[j] = f2bf(W[k * FEAT + n]);
        }
        *(uint4*)&bfW[(long)idx * 8] = *(uint4*)frag;
    }
}

// ===========================================================================
// FUSED gather + MFMA GEMM, one layer:
//   out_rows[i] = (sum_{e in CSR(i)} h[sorted_src[e]]) @ W + bias  [opt ReLU]
//
// Block = 64 nodes (4 waves x 16). Lane (l15 = lane&15, quad = lane>>4) of
// wave w gathers node (blk*64 + w*16 + l15), feature chunk kc*32+quad*8..+8
// for kc=0..3 — i.e. the fp32 accumulator IS the MFMA A-fragment
// (A[m=l15][k=quad*8+j] per 32-wide k-chunk). No agg buffer, no transpose.
// Per edge the node's 4 lanes read the full 256 B row as 4 dwordx4 each.
// 8 edges per index-batch (2 idx regs + shuffles) for MLP.
// Epilogue routes C through LDS (stride 132) for coalesced stores.
// ===========================================================================
template <bool RELU, bool OUT_BF16>
__global__ __launch_bounds__(256) void gather_gemm(const unsigned short* __restrict__ h,
                                                   const int* __restrict__ offsets,
                                                   const int* __restrict__ sorted_src,
                                                   const unsigned short* __restrict__ bfW,
                                                   const float* __restrict__ bias,
                                                   void* __restrict__ out, int N) {
    __shared__ __align__(16) union {
        unsigned short b[16384];   // 32 KB frag-ordered W
        float o[64 * 132];         // 33.8 KB epilogue transpose
    } sm;

    const int t = threadIdx.x;
    // Stage frag-ordered W (linear, coalesced). Synced before MFMA phase.
#pragma unroll
    for (int it = 0; it < 8; it++) {
        const int o = (it * 256 + t) * 8;
        *(uint4*)&sm.b[o] = *(const uint4*)&bfW[o];
    }

    const int wave = t >> 6;
    const int lane = t & 63;
    const int quad = lane >> 4;
    const int l15 = lane & 15;
    const int node = blockIdx.x * 64 + wave * 16 + l15;

    int start = 0, end = 0;
    if (node < N) { start = offsets[node]; end = offsets[node + 1]; }

    const uint4* hb = (const uint4*)h;   // 16 uint4 per 128-feat row
    float acc[4][8];
#pragma unroll
    for (int kc = 0; kc < 4; kc++)
#pragma unroll
        for (int j = 0; j < 8; j++) acc[kc][j] = 0.f;

    // ---- gather phase ----
    for (int eb = start; eb < end; eb += 8) {
        const int e0 = eb + quad * 2;
        const int s0 = (e0 < end) ? sorted_src[e0] : 0;
        const int s1 = (e0 + 1 < end) ? sorted_src[e0 + 1] : 0;
        const int cnt = min(8, end - eb);
#pragma unroll 8
        for (int j = 0; j < cnt; j++) {
            const int sl = (j >> 1) * 16 + l15;        // lane holding edge eb+j
            const int s = __shfl((j & 1) ? s1 : s0, sl);
            const long rb = (long)s * 16;
            uint4 u[4];
#pragma unroll
            for (int kc = 0; kc < 4; kc++) u[kc] = hb[rb + kc * 4 + quad];
#pragma unroll
            for (int kc = 0; kc < 4; kc++) {
                acc[kc][0] += bf_lo(u[kc].x); acc[kc][1] += bf_hi(u[kc].x);
                acc[kc][2] += bf_lo(u[kc].y); acc[kc][3] += bf_hi(u[kc].y);
                acc[kc][4] += bf_lo(u[kc].z); acc[kc][5] += bf_hi(u[kc].z);
                acc[kc][6] += bf_lo(u[kc].w); acc[kc][7] += bf_hi(u[kc].w);
            }
        }
    }

    // acc -> A fragments (register-only; layout already matches).
    short8 afrag[4];
#pragma unroll
    for (int kc = 0; kc < 4; kc++) {
        unsigned short fr[8];
#pragma unroll
        for (int j = 0; j < 8; j++) fr[j] = f2bf(acc[kc][j]);
        afrag[kc] = *(short8*)fr;
    }

    __syncthreads();  // W staged & all waves ready

    // ---- MFMA phase: 16 rows x 128 cols per wave ----
    floatx4 cacc[8];
#pragma unroll
    for (int ct = 0; ct < 8; ct++) cacc[ct] = (floatx4){0.f, 0.f, 0.f, 0.f};
#pragma unroll
    for (int kc = 0; kc < 4; kc++) {
#pragma unroll
        for (int ct = 0; ct < 8; ct++) {
            const short8 b = *(const short8*)&sm.b[((kc * 8 + ct) * 64 + lane) * 8];
            cacc[ct] = __builtin_amdgcn_mfma_f32_16x16x32_bf16(afrag[kc], b, cacc[ct], 0, 0, 0);
        }
    }

    __syncthreads();  // all waves done reading sm.b
    // C/D layout: col = l15, row = quad*4 + r. Bias/ReLU, park in LDS.
#pragma unroll
    for (int ct = 0; ct < 8; ct++) {
        const int col = ct * 16 + l15;
        const float bv = bias[col];
#pragma unroll
        for (int r = 0; r < 4; r++) {
            float v = cacc[ct][r] + bv;
            if (RELU) v = fmaxf(v, 0.f);
            sm.o[(wave * 16 + quad * 4 + r) * 132 + col] = v;
        }
    }
    __syncthreads();

    // Coalesced store: thread covers row rb = t>>2, cols [(t&3)*32, +32).
    const int rb = t >> 2;
    const int c0 = (t & 3) * 32;
    const int grow = blockIdx.x * 64 + rb;
    if (grow < N) {
        const float* lr = &sm.o[rb * 132 + c0];
        if (OUT_BF16) {
            unsigned short* op = (unsigned short*)out + (long)grow * FEAT + c0;
#pragma unroll
            for (int k = 0; k < 4; k++) {
                const float4 a = *(const float4*)&lr[k * 8];
                const float4 b = *(const float4*)&lr[k * 8 + 4];
                uint4 p;
                p.x = pack2(a.x, a.y);
                p.y = pack2(a.z, a.w);
                p.z = pack2(b.x, b.y);
                p.w = pack2(b.z, b.w);
                *(uint4*)&op[k * 8] = p;
            }
        } else {
            float* op = (float*)out + (long)grow * FEAT + c0;
#pragma unroll
            for (int k = 0; k < 8; k++)
                *(float4*)&op[k * 4] = *(const float4*)&lr[k * 4];
        }
    }
}

// ===========================================================================
// Pipeline (bf16 payloads, fp32 accumulation):
//   CSR(dst) once; xb = bf16(x)
//   h1b = fused_gather_gemm(xb, W1, b1, relu) -> bf16
//   out = fused_gather_gemm(h1b, W2, b2)      -> fp32
// Linearity: segment_sum((hW)[src]) == (segment_sum h[src]) @ W.
// ===========================================================================
extern "C" void kernel_launch(void* const* d_in, const int* in_sizes, int n_in,
                              void* d_out, int out_size, void* d_ws, size_t ws_size,
                              hipStream_t stream) {
    const float* x  = (const float*)d_in[0];
    const int*   ei = (const int*)d_in[1];
    const float* W1 = (const float*)d_in[2];
    const float* b1 = (const float*)d_in[3];
    const float* W2 = (const float*)d_in[4];
    const float* b2 = (const float*)d_in[5];
    float* out = (float*)d_out;

    const int N = in_sizes[0] / FEAT;
    const int E = in_sizes[1] / 2;
    const int* src = ei;
    const int* dst = ei + E;

    // Workspace carve-up (~55 MB).
    unsigned short* xb   = (unsigned short*)d_ws;            // N*128 bf16
    unsigned short* h1b  = xb + (size_t)N * FEAT;            // N*128 bf16
    unsigned short* bfW1 = h1b + (size_t)N * FEAT;           // 16384
    unsigned short* bfW2 = bfW1 + 16384;                     // 16384
    int* counts    = (int*)(bfW2 + 16384);                   // [N]
    int* offsets   = counts + N;                             // [N+1]
    int* cursor    = offsets + N + 1;                        // [N]
    int* blocksums = cursor + N;                             // [<=128]
    int* sorted_src = blocksums + 128;                       // [E]

    const int NB = (N + 1023) / 1024;
    const int eb = (E + 255) / 256;
    const int nb = (N + 255) / 256;

    // ---- CSR build ----
    hipMemsetAsync(counts, 0, (size_t)N * sizeof(int), stream);
    hist_kernel<<<eb, 256, 0, stream>>>(dst, counts, E);
    scan_chunk<<<NB, 256, 0, stream>>>(counts, offsets, blocksums, N);
    scan_blocksums<<<1, 256, 0, stream>>>(blocksums, NB);
    add_base<<<nb, 256, 0, stream>>>(offsets, cursor, blocksums, N, E);
    permute_kernel<<<eb, 256, 0, stream>>>(src, dst, cursor, sorted_src, E);

    // ---- bf16 prep ----
    const long n4 = (long)N * FEAT / 4;
    convert_bf16<<<(int)((n4 + 255) / 256), 256, 0, stream>>>(x, xb, n4);
    prep_w2<<<2, 256, 0, stream>>>(W1, W2, bfW1, bfW2);

    const int fused_blocks = (N + 63) / 64;

    // ---- Layer 1 (bf16 out) / Layer 2 (fp32 out) ----
    gather_gemm<true, true><<<fused_blocks, 256, 0, stream>>>(
        xb, offsets, sorted_src, bfW1, b1, h1b, N);
    gather_gemm<false, false><<<fused_blocks, 256, 0, stream>>>(
        h1b, offsets, sorted_src, bfW2, b2, out, N);
}

// Round 6
// 263.103 us; speedup vs baseline: 4.6740x; 1.0107x over previous
//
#include <hip/hip_runtime.h>

#define FEAT 128

typedef __attribute__((ext_vector_type(8))) short short8;
typedef __attribute__((ext_vector_type(4))) float floatx4;

// bf16 helpers (manual, RNE) — finite data only.
__device__ __forceinline__ unsigned short f2bf(float f) {
    unsigned int u = __float_as_uint(f);
    u += 0x7fffu + ((u >> 16) & 1u);
    return (unsigned short)(u >> 16);
}
__device__ __forceinline__ float bf_lo(unsigned int u) { return __uint_as_float(u << 16); }
__device__ __forceinline__ float bf_hi(unsigned int u) { return __uint_as_float(u & 0xffff0000u); }
__device__ __forceinline__ unsigned int pack2(float a, float b) {
    return (unsigned int)f2bf(a) | ((unsigned int)f2bf(b) << 16);
}

// ===========================================================================
// CSR build (counting sort on dst), once per call, reused by both layers.
// ===========================================================================
__global__ __launch_bounds__(256) void hist_kernel(const int* __restrict__ dst,
                                                   int* __restrict__ counts, int E) {
    const int e = blockIdx.x * 256 + threadIdx.x;
    if (e < E) atomicAdd(&counts[dst[e]], 1);
}

__global__ __launch_bounds__(256) void scan_chunk(const int* __restrict__ counts,
                                                  int* __restrict__ offsets,
                                                  int* __restrict__ blocksums, int N) {
    const int t = threadIdx.x;
    const int base = blockIdx.x * 1024 + t * 4;
    int c0 = (base + 0 < N) ? counts[base + 0] : 0;
    int c1 = (base + 1 < N) ? counts[base + 1] : 0;
    int c2 = (base + 2 < N) ? counts[base + 2] : 0;
    int c3 = (base + 3 < N) ? counts[base + 3] : 0;
    const int sum = c0 + c1 + c2 + c3;

    const int lane = t & 63, wv = t >> 6;
    int v = sum;
#pragma unroll
    for (int off = 1; off < 64; off <<= 1) {
        int n = __shfl_up(v, off);
        if (lane >= off) v += n;
    }
    __shared__ int ws[4];
    if (lane == 63) ws[wv] = v;
    __syncthreads();
    int wp = 0;
    for (int w = 0; w < wv; w++) wp += ws[w];
    int excl = wp + v - sum;

    if (base + 0 < N) offsets[base + 0] = excl;
    if (base + 1 < N) offsets[base + 1] = excl + c0;
    if (base + 2 < N) offsets[base + 2] = excl + c0 + c1;
    if (base + 3 < N) offsets[base + 3] = excl + c0 + c1 + c2;
    if (t == 255) blocksums[blockIdx.x] = wp + v;
}

__global__ __launch_bounds__(256) void scan_blocksums(int* __restrict__ bs, int nb) {
    const int t = threadIdx.x;
    int orig = (t < nb) ? bs[t] : 0;
    int v = orig;
    const int lane = t & 63, wv = t >> 6;
#pragma unroll
    for (int off = 1; off < 64; off <<= 1) {
        int n = __shfl_up(v, off);
        if (lane >= off) v += n;
    }
    __shared__ int ws[4];
    if (lane == 63) ws[wv] = v;
    __syncthreads();
    int wp = 0;
    for (int w = 0; w < wv; w++) wp += ws[w];
    if (t < nb) bs[t] = wp + v - orig;
}

__global__ __launch_bounds__(256) void add_base(int* __restrict__ offsets,
                                                int* __restrict__ cursor,
                                                const int* __restrict__ blocksums,
                                                int N, int E) {
    const int i = blockIdx.x * 256 + threadIdx.x;
    if (i < N) {
        const int off = offsets[i] + blocksums[i >> 10];
        offsets[i] = off;
        cursor[i] = off;
    }
    if (i == 0) offsets[N] = E;
}

__global__ __launch_bounds__(256) void permute_kernel(const int* __restrict__ src,
                                                      const int* __restrict__ dst,
                                                      int* __restrict__ cursor,
                                                      int* __restrict__ sorted_src, int E) {
    const int e = blockIdx.x * 256 + threadIdx.x;
    if (e < E) {
        const int pos = atomicAdd(&cursor[dst[e]], 1);
        sorted_src[pos] = src[e];
    }
}

// ===========================================================================
// fp32 [N,128] -> bf16 (RNE), 4 elems/thread.
// ===========================================================================
__global__ __launch_bounds__(256) void convert_bf16(const float* __restrict__ in,
                                                    unsigned short* __restrict__ out,
                                                    long n4) {
    const long i = (long)blockIdx.x * 256 + threadIdx.x;
    if (i >= n4) return;
    const float4 v = *(const float4*)&in[i * 4];
    uint2 p;
    p.x = pack2(v.x, v.y);
    p.y = pack2(v.z, v.w);
    *(uint2*)&out[i * 4] = p;
}

// ===========================================================================
// Both W matrices -> fragment-ordered bf16 for mfma_f32_16x16x32_bf16.
// bfW[((kc*8+ct)*64+lane)*8 + j] = bf16(W[kc*32 + (lane>>4)*8 + j][ct*16 + (lane&15)])
// blockIdx 0 -> W1, 1 -> W2.
// ===========================================================================
__global__ __launch_bounds__(256) void prep_w2(const float* __restrict__ W1,
                                               const float* __restrict__ W2,
                                               unsigned short* __restrict__ bfW1,
                                               unsigned short* __restrict__ bfW2) {
    const float* W = blockIdx.x ? W2 : W1;
    unsigned short* bfW = blockIdx.x ? bfW2 : bfW1;
    const int t = threadIdx.x;
#pragma unroll
    for (int it = 0; it < 8; it++) {
        const int idx = it * 256 + t;
        const int kc = idx >> 9;
        const int ct = (idx >> 6) & 7;
        const int lane = idx & 63;
        const int quad = lane >> 4;
        const int n = ct * 16 + (lane & 15);
        unsigned short frag[8];
#pragma unroll
        for (int j = 0; j < 8; j++) {
            const int k = kc * 32 + quad * 8 + j;
            frag[j] = f2bf(W[k * FEAT + n]);
        }
        *(uint4*)&bfW[(long)idx * 8] = *(uint4*)frag;
    }
}

// ===========================================================================
// FUSED gather + MFMA GEMM, one layer — ZERO LDS, no barriers:
//   out_rows[i] = (sum_{e in CSR(i)} h[sorted_src[e]]) @ W + bias  [opt ReLU]
//
// Block = 64 nodes (4 waves x 16, waves fully independent). Lane
// (l15 = lane&15, quad = lane>>4) of wave w gathers node (blk*64+w*16+l15),
// feature chunk kc*32+quad*8..+8 for kc=0..3 — the fp32 accumulator IS the
// MFMA A-fragment. Edge indices software-pipelined (next batch prefetched).
// B-fragments read directly from frag-ordered bfW in global (1 KB coalesced
// per instr, L1/L2-resident — 32 KB shared by all blocks). Epilogue stores
// from registers in C-layout: per instr 4 quads x 16 consecutive cols.
// __launch_bounds__(256,6): cap VGPR <=85 -> 24 waves/CU target.
// ===========================================================================
template <bool RELU, bool OUT_BF16>
__global__ __launch_bounds__(256, 6) void gather_gemm(const unsigned short* __restrict__ h,
                                                      const int* __restrict__ offsets,
                                                      const int* __restrict__ sorted_src,
                                                      const unsigned short* __restrict__ bfW,
                                                      const float* __restrict__ bias,
                                                      void* __restrict__ out, int N) {
    const int t = threadIdx.x;
    const int wave = t >> 6;
    const int lane = t & 63;
    const int quad = lane >> 4;
    const int l15 = lane & 15;
    const int node = blockIdx.x * 64 + wave * 16 + l15;

    int start = 0, end = 0;
    if (node < N) { start = offsets[node]; end = offsets[node + 1]; }

    const uint4* hb = (const uint4*)h;   // 16 uint4 per 128-feat row
    float acc[4][8];
#pragma unroll
    for (int kc = 0; kc < 4; kc++)
#pragma unroll
        for (int j = 0; j < 8; j++) acc[kc][j] = 0.f;

    // ---- gather phase (lane holds edges quad*2, quad*2+1 of node l15) ----
    int e0 = start + quad * 2;
    int s0 = (e0 < end) ? sorted_src[e0] : 0;
    int s1 = (e0 + 1 < end) ? sorted_src[e0 + 1] : 0;

    for (int eb = start; eb < end; eb += 8) {
        // Prefetch next batch's indices (hides index-load latency).
        const int ne = eb + 8 + quad * 2;
        const int ns0 = (ne < end) ? sorted_src[ne] : 0;
        const int ns1 = (ne + 1 < end) ? sorted_src[ne + 1] : 0;

        const int cnt = min(8, end - eb);
#pragma unroll 8
        for (int j = 0; j < cnt; j++) {
            const int sl = (j >> 1) * 16 + l15;        // lane holding edge eb+j of node l15
            const int s = __shfl((j & 1) ? s1 : s0, sl);
            const long rb = (long)s * 16;
            uint4 u[4];
#pragma unroll
            for (int kc = 0; kc < 4; kc++) u[kc] = hb[rb + kc * 4 + quad];
#pragma unroll
            for (int kc = 0; kc < 4; kc++) {
                acc[kc][0] += bf_lo(u[kc].x); acc[kc][1] += bf_hi(u[kc].x);
                acc[kc][2] += bf_lo(u[kc].y); acc[kc][3] += bf_hi(u[kc].y);
                acc[kc][4] += bf_lo(u[kc].z); acc[kc][5] += bf_hi(u[kc].z);
                acc[kc][6] += bf_lo(u[kc].w); acc[kc][7] += bf_hi(u[kc].w);
            }
        }
        s0 = ns0; s1 = ns1;
    }

    // acc -> A fragments (register-only; layout already matches).
    short8 afrag[4];
#pragma unroll
    for (int kc = 0; kc < 4; kc++) {
        unsigned short fr[8];
#pragma unroll
        for (int j = 0; j < 8; j++) fr[j] = f2bf(acc[kc][j]);
        afrag[kc] = *(short8*)fr;
    }

    // ---- MFMA phase: B-frags straight from global (L1/L2-hot 32 KB) ----
    floatx4 cacc[8];
#pragma unroll
    for (int ct = 0; ct < 8; ct++) cacc[ct] = (floatx4){0.f, 0.f, 0.f, 0.f};
#pragma unroll
    for (int kc = 0; kc < 4; kc++) {
#pragma unroll
        for (int ct = 0; ct < 8; ct++) {
            const short8 b = *(const short8*)&bfW[((kc * 8 + ct) * 64 + lane) * 8];
            cacc[ct] = __builtin_amdgcn_mfma_f32_16x16x32_bf16(afrag[kc], b, cacc[ct], 0, 0, 0);
        }
    }

    // ---- epilogue: C/D layout col=l15(+16*ct), row=quad*4+r, direct stores.
    // Per store instr: 4 quads = 4 rows x 16 consecutive cols (64B/32B segs).
#pragma unroll
    for (int ct = 0; ct < 8; ct++) {
        const int col = ct * 16 + l15;
        const float bv = bias[col];
#pragma unroll
        for (int r = 0; r < 4; r++) {
            const int row = blockIdx.x * 64 + wave * 16 + quad * 4 + r;
            if (row < N) {
                float v = cacc[ct][r] + bv;
                if (RELU) v = fmaxf(v, 0.f);
                if (OUT_BF16)
                    ((unsigned short*)out)[(long)row * FEAT + col] = f2bf(v);
                else
                    ((float*)out)[(long)row * FEAT + col] = v;
            }
        }
    }
}

// ===========================================================================
// Pipeline (bf16 payloads, fp32 accumulation):
//   CSR(dst) once; xb = bf16(x)
//   h1b = fused_gather_gemm(xb, W1, b1, relu) -> bf16
//   out = fused_gather_gemm(h1b, W2, b2)      -> fp32
// Linearity: segment_sum((hW)[src]) == (segment_sum h[src]) @ W.
// ===========================================================================
extern "C" void kernel_launch(void* const* d_in, const int* in_sizes, int n_in,
                              void* d_out, int out_size, void* d_ws, size_t ws_size,
                              hipStream_t stream) {
    const float* x  = (const float*)d_in[0];
    const int*   ei = (const int*)d_in[1];
    const float* W1 = (const float*)d_in[2];
    const float* b1 = (const float*)d_in[3];
    const float* W2 = (const float*)d_in[4];
    const float* b2 = (const float*)d_in[5];
    float* out = (float*)d_out;

    const int N = in_sizes[0] / FEAT;
    const int E = in_sizes[1] / 2;
    const int* src = ei;
    const int* dst = ei + E;

    // Workspace carve-up (~55 MB).
    unsigned short* xb   = (unsigned short*)d_ws;            // N*128 bf16
    unsigned short* h1b  = xb + (size_t)N * FEAT;            // N*128 bf16
    unsigned short* bfW1 = h1b + (size_t)N * FEAT;           // 16384
    unsigned short* bfW2 = bfW1 + 16384;                     // 16384
    int* counts    = (int*)(bfW2 + 16384);                   // [N]
    int* offsets   = counts + N;                             // [N+1]
    int* cursor    = offsets + N + 1;                        // [N]
    int* blocksums = cursor + N;                             // [<=128]
    int* sorted_src = blocksums + 128;                       // [E]

    const int NB = (N + 1023) / 1024;
    const int eb = (E + 255) / 256;
    const int nb = (N + 255) / 256;

    // ---- CSR build ----
    hipMemsetAsync(counts, 0, (size_t)N * sizeof(int), stream);
    hist_kernel<<<eb, 256, 0, stream>>>(dst, counts, E);
    scan_chunk<<<NB, 256, 0, stream>>>(counts, offsets, blocksums, N);
    scan_blocksums<<<1, 256, 0, stream>>>(blocksums, NB);
    add_base<<<nb, 256, 0, stream>>>(offsets, cursor, blocksums, N, E);
    permute_kernel<<<eb, 256, 0, stream>>>(src, dst, cursor, sorted_src, E);

    // ---- bf16 prep ----
    const long n4 = (long)N * FEAT / 4;
    convert_bf16<<<(int)((n4 + 255) / 256), 256, 0, stream>>>(x, xb, n4);
    prep_w2<<<2, 256, 0, stream>>>(W1, W2, bfW1, bfW2);

    const int fused_blocks = (N + 63) / 64;

    // ---- Layer 1 (bf16 out) / Layer 2 (fp32 out) ----
    gather_gemm<true, true><<<fused_blocks, 256, 0, stream>>>(
        xb, offsets, sorted_src, bfW1, b1, h1b, N);
    gather_gemm<false, false><<<fused_blocks, 256, 0, stream>>>(
        h1b, offsets, sorted_src, bfW2, b2, out, N);
}

// Round 7
// 261.693 us; speedup vs baseline: 4.6992x; 1.0054x over previous
//
#include <hip/hip_runtime.h>

#define FEAT 128

typedef __attribute__((ext_vector_type(8))) short short8;
typedef __attribute__((ext_vector_type(4))) float floatx4;

// bf16 helpers (manual, RNE) — finite data only.
__device__ __forceinline__ unsigned short f2bf(float f) {
    unsigned int u = __float_as_uint(f);
    u += 0x7fffu + ((u >> 16) & 1u);
    return (unsigned short)(u >> 16);
}
__device__ __forceinline__ float bf_lo(unsigned int u) { return __uint_as_float(u << 16); }
__device__ __forceinline__ float bf_hi(unsigned int u) { return __uint_as_float(u & 0xffff0000u); }
__device__ __forceinline__ unsigned int pack2(float a, float b) {
    return (unsigned int)f2bf(a) | ((unsigned int)f2bf(b) << 16);
}

// ===========================================================================
// Fused convert + histogram: stream x -> bf16 while the same threads issue
// the dst-histogram atomics (atomic latency hides under streaming traffic).
// ===========================================================================
__global__ __launch_bounds__(256) void convert_hist(const float* __restrict__ x,
                                                    unsigned short* __restrict__ xb,
                                                    long n4,
                                                    const int* __restrict__ dst,
                                                    int* __restrict__ counts, int E) {
    const long i = (long)blockIdx.x * 256 + threadIdx.x;
    if (i < E) atomicAdd(&counts[dst[i]], 1);
    if (i < n4) {
        const float4 v = *(const float4*)&x[i * 4];
        uint2 p;
        p.x = pack2(v.x, v.y);
        p.y = pack2(v.z, v.w);
        *(uint2*)&xb[i * 4] = p;
    }
}

// ===========================================================================
// Exclusive scan level 1: 256 threads x 4 elems = 1024-chunk per block.
// ===========================================================================
__global__ __launch_bounds__(256) void scan_chunk(const int* __restrict__ counts,
                                                  int* __restrict__ offsets,
                                                  int* __restrict__ blocksums, int N) {
    const int t = threadIdx.x;
    const int base = blockIdx.x * 1024 + t * 4;
    int c0 = (base + 0 < N) ? counts[base + 0] : 0;
    int c1 = (base + 1 < N) ? counts[base + 1] : 0;
    int c2 = (base + 2 < N) ? counts[base + 2] : 0;
    int c3 = (base + 3 < N) ? counts[base + 3] : 0;
    const int sum = c0 + c1 + c2 + c3;

    const int lane = t & 63, wv = t >> 6;
    int v = sum;
#pragma unroll
    for (int off = 1; off < 64; off <<= 1) {
        int n = __shfl_up(v, off);
        if (lane >= off) v += n;
    }
    __shared__ int ws[4];
    if (lane == 63) ws[wv] = v;
    __syncthreads();
    int wp = 0;
    for (int w = 0; w < wv; w++) wp += ws[w];
    int excl = wp + v - sum;

    if (base + 0 < N) offsets[base + 0] = excl;
    if (base + 1 < N) offsets[base + 1] = excl + c0;
    if (base + 2 < N) offsets[base + 2] = excl + c0 + c1;
    if (base + 3 < N) offsets[base + 3] = excl + c0 + c1 + c2;
    if (t == 255) blocksums[blockIdx.x] = wp + v;
}

// ===========================================================================
// Scan level 2 fused into add_base: each block (256 nodes, all in chunk
// c = blockIdx>>2) re-derives prefix(blocksums[0..c)) with wave 0 (<=2
// elems/lane for 98 chunks), then adds it. Also duplicates into cursor and
// caps offsets[N] = E.
// ===========================================================================
__global__ __launch_bounds__(256) void add_base(int* __restrict__ offsets,
                                                int* __restrict__ cursor,
                                                const int* __restrict__ blocksums,
                                                int N, int E) {
    __shared__ int sbase;
    const int c = blockIdx.x >> 2;       // this block's chunk id
    const int t = threadIdx.x;
    if (t < 64) {
        int s = 0;
        for (int j = t; j < c; j += 64) s += blocksums[j];
#pragma unroll
        for (int off = 32; off; off >>= 1) s += __shfl_down(s, off);
        if (t == 0) sbase = s;
    }
    __syncthreads();
    const int base = sbase;
    const int i = blockIdx.x * 256 + t;
    if (i < N) {
        const int off = offsets[i] + base;
        offsets[i] = off;
        cursor[i] = off;
    }
    if (i == 0) offsets[N] = E;
}

__global__ __launch_bounds__(256) void permute_kernel(const int* __restrict__ src,
                                                      const int* __restrict__ dst,
                                                      int* __restrict__ cursor,
                                                      int* __restrict__ sorted_src, int E) {
    const int e = blockIdx.x * 256 + threadIdx.x;
    if (e < E) {
        const int pos = atomicAdd(&cursor[dst[e]], 1);
        sorted_src[pos] = src[e];
    }
}

// ===========================================================================
// Both W matrices -> fragment-ordered bf16 for mfma_f32_16x16x32_bf16.
// bfW[((kc*8+ct)*64+lane)*8 + j] = bf16(W[kc*32 + (lane>>4)*8 + j][ct*16 + (lane&15)])
// blockIdx 0 -> W1, 1 -> W2.
// ===========================================================================
__global__ __launch_bounds__(256) void prep_w2(const float* __restrict__ W1,
                                               const float* __restrict__ W2,
                                               unsigned short* __restrict__ bfW1,
                                               unsigned short* __restrict__ bfW2) {
    const float* W = blockIdx.x ? W2 : W1;
    unsigned short* bfW = blockIdx.x ? bfW2 : bfW1;
    const int t = threadIdx.x;
#pragma unroll
    for (int it = 0; it < 8; it++) {
        const int idx = it * 256 + t;
        const int kc = idx >> 9;
        const int ct = (idx >> 6) & 7;
        const int lane = idx & 63;
        const int quad = lane >> 4;
        const int n = ct * 16 + (lane & 15);
        unsigned short frag[8];
#pragma unroll
        for (int j = 0; j < 8; j++) {
            const int k = kc * 32 + quad * 8 + j;
            frag[j] = f2bf(W[k * FEAT + n]);
        }
        *(uint4*)&bfW[(long)idx * 8] = *(uint4*)frag;
    }
}

// ===========================================================================
// FUSED gather + MFMA GEMM — zero LDS, no barriers, 128-THREAD blocks:
//   out_rows[i] = (sum_{e in CSR(i)} h[sorted_src[e]]) @ W + bias  [opt ReLU]
//
// Waves are fully independent; block size is only a scheduling quantum.
// 128 threads = 2 waves = 32 nodes/block -> 3125 blocks = 12.2 blocks/CU
// (fine-grained balance under the 16-WG/CU cap; round-6's 64-node blocks
// gave 6.1 blocks/CU and 42% occupancy).
// Lane (l15, quad) gathers node (blk*32 + wave*16 + l15), feature chunk
// kc*32+quad*8..+8 — the fp32 accumulator IS the MFMA A-fragment.
// B-frags straight from frag-ordered bfW in global (L1/L2-hot 32 KB).
// Epilogue stores from registers in C-layout (4 rows x 16-col segments).
// ===========================================================================
template <bool RELU, bool OUT_BF16>
__global__ __launch_bounds__(128, 8) void gather_gemm(const unsigned short* __restrict__ h,
                                                      const int* __restrict__ offsets,
                                                      const int* __restrict__ sorted_src,
                                                      const unsigned short* __restrict__ bfW,
                                                      const float* __restrict__ bias,
                                                      void* __restrict__ out, int N) {
    const int t = threadIdx.x;
    const int wave = t >> 6;
    const int lane = t & 63;
    const int quad = lane >> 4;
    const int l15 = lane & 15;
    const int node = blockIdx.x * 32 + wave * 16 + l15;

    int start = 0, end = 0;
    if (node < N) { start = offsets[node]; end = offsets[node + 1]; }

    const uint4* hb = (const uint4*)h;   // 16 uint4 per 128-feat row
    float acc[4][8];
#pragma unroll
    for (int kc = 0; kc < 4; kc++)
#pragma unroll
        for (int j = 0; j < 8; j++) acc[kc][j] = 0.f;

    // ---- gather phase (lane holds edges quad*2, quad*2+1 of node l15) ----
    int e0 = start + quad * 2;
    int s0 = (e0 < end) ? sorted_src[e0] : 0;
    int s1 = (e0 + 1 < end) ? sorted_src[e0 + 1] : 0;

    for (int eb = start; eb < end; eb += 8) {
        // Prefetch next batch's indices (hides index-load latency).
        const int ne = eb + 8 + quad * 2;
        const int ns0 = (ne < end) ? sorted_src[ne] : 0;
        const int ns1 = (ne + 1 < end) ? sorted_src[ne + 1] : 0;

        const int cnt = min(8, end - eb);
#pragma unroll 8
        for (int j = 0; j < cnt; j++) {
            const int sl = (j >> 1) * 16 + l15;        // lane holding edge eb+j of node l15
            const int s = __shfl((j & 1) ? s1 : s0, sl);
            const long rb = (long)s * 16;
            uint4 u[4];
#pragma unroll
            for (int kc = 0; kc < 4; kc++) u[kc] = hb[rb + kc * 4 + quad];
#pragma unroll
            for (int kc = 0; kc < 4; kc++) {
                acc[kc][0] += bf_lo(u[kc].x); acc[kc][1] += bf_hi(u[kc].x);
                acc[kc][2] += bf_lo(u[kc].y); acc[kc][3] += bf_hi(u[kc].y);
                acc[kc][4] += bf_lo(u[kc].z); acc[kc][5] += bf_hi(u[kc].z);
                acc[kc][6] += bf_lo(u[kc].w); acc[kc][7] += bf_hi(u[kc].w);
            }
        }
        s0 = ns0; s1 = ns1;
    }

    // acc -> A fragments (register-only; layout already matches).
    short8 afrag[4];
#pragma unroll
    for (int kc = 0; kc < 4; kc++) {
        unsigned short fr[8];
#pragma unroll
        for (int j = 0; j < 8; j++) fr[j] = f2bf(acc[kc][j]);
        afrag[kc] = *(short8*)fr;
    }

    // ---- MFMA phase: B-frags straight from global (L1/L2-hot 32 KB) ----
    floatx4 cacc[8];
#pragma unroll
    for (int ct = 0; ct < 8; ct++) cacc[ct] = (floatx4){0.f, 0.f, 0.f, 0.f};
#pragma unroll
    for (int kc = 0; kc < 4; kc++) {
#pragma unroll
        for (int ct = 0; ct < 8; ct++) {
            const short8 b = *(const short8*)&bfW[((kc * 8 + ct) * 64 + lane) * 8];
            cacc[ct] = __builtin_amdgcn_mfma_f32_16x16x32_bf16(afrag[kc], b, cacc[ct], 0, 0, 0);
        }
    }

    // ---- epilogue: C/D layout col=ct*16+l15, row=quad*4+r, direct stores.
#pragma unroll
    for (int ct = 0; ct < 8; ct++) {
        const int col = ct * 16 + l15;
        const float bv = bias[col];
#pragma unroll
        for (int r = 0; r < 4; r++) {
            const int row = blockIdx.x * 32 + wave * 16 + quad * 4 + r;
            if (row < N) {
                float v = cacc[ct][r] + bv;
                if (RELU) v = fmaxf(v, 0.f);
                if (OUT_BF16)
                    ((unsigned short*)out)[(long)row * FEAT + col] = f2bf(v);
                else
                    ((float*)out)[(long)row * FEAT + col] = v;
            }
        }
    }
}

// ===========================================================================
// Pipeline (bf16 payloads, fp32 accumulation):
//   counts=0; convert+hist; scan; add_base(+scan2); permute; prep_w
//   h1b = fused_gather_gemm(xb, W1, b1, relu) -> bf16
//   out = fused_gather_gemm(h1b, W2, b2)      -> fp32
// Linearity: segment_sum((hW)[src]) == (segment_sum h[src]) @ W.
// ===========================================================================
extern "C" void kernel_launch(void* const* d_in, const int* in_sizes, int n_in,
                              void* d_out, int out_size, void* d_ws, size_t ws_size,
                              hipStream_t stream) {
    const float* x  = (const float*)d_in[0];
    const int*   ei = (const int*)d_in[1];
    const float* W1 = (const float*)d_in[2];
    const float* b1 = (const float*)d_in[3];
    const float* W2 = (const float*)d_in[4];
    const float* b2 = (const float*)d_in[5];
    float* out = (float*)d_out;

    const int N = in_sizes[0] / FEAT;
    const int E = in_sizes[1] / 2;
    const int* src = ei;
    const int* dst = ei + E;

    // Workspace carve-up (~55 MB).
    unsigned short* xb   = (unsigned short*)d_ws;            // N*128 bf16
    unsigned short* h1b  = xb + (size_t)N * FEAT;            // N*128 bf16
    unsigned short* bfW1 = h1b + (size_t)N * FEAT;           // 16384
    unsigned short* bfW2 = bfW1 + 16384;                     // 16384
    int* counts    = (int*)(bfW2 + 16384);                   // [N]
    int* offsets   = counts + N;                             // [N+1]
    int* cursor    = offsets + N + 1;                        // [N]
    int* blocksums = cursor + N;                             // [<=128]
    int* sorted_src = blocksums + 128;                       // [E]

    const int NB = (N + 1023) / 1024;
    const int eb = (E + 255) / 256;
    const int nb = (N + 255) / 256;
    const long n4 = (long)N * FEAT / 4;

    // ---- CSR build + bf16 prep ----
    hipMemsetAsync(counts, 0, (size_t)N * sizeof(int), stream);
    convert_hist<<<(int)((n4 + 255) / 256), 256, 0, stream>>>(x, xb, n4, dst, counts, E);
    scan_chunk<<<NB, 256, 0, stream>>>(counts, offsets, blocksums, N);
    add_base<<<nb, 256, 0, stream>>>(offsets, cursor, blocksums, N, E);
    permute_kernel<<<eb, 256, 0, stream>>>(src, dst, cursor, sorted_src, E);
    prep_w2<<<2, 256, 0, stream>>>(W1, W2, bfW1, bfW2);

    const int fused_blocks = (N + 31) / 32;

    // ---- Layer 1 (bf16 out) / Layer 2 (fp32 out) ----
    gather_gemm<true, true><<<fused_blocks, 128, 0, stream>>>(
        xb, offsets, sorted_src, bfW1, b1, h1b, N);
    gather_gemm<false, false><<<fused_blocks, 128, 0, stream>>>(
        h1b, offsets, sorted_src, bfW2, b2, out, N);
}